// Round 1
// 16179.745 us; speedup vs baseline: 1.0481x; 1.0481x over previous
//
#include <hip/hip_runtime.h>
#include <stdint.h>
#include <stddef.h>

// TPGRUCell forward, MI355X gfx950.
// Inputs f32, output f32 (verified round 3: absmax 1.95e-3).
// Phase 1: 5 MFMA GEMMs (f32 staged->bf16). Phase 2: ONE persistent kernel,
// 32 WGs, own device-scope grid barrier, 512 steps x (stageA GEMM -> bar ->
// stageB GEMMs + gates -> bar). Weights pre-transposed [n][k] bf16 so MFMA
// fragments load straight from global (L2-hot) - no LDS in the hot loop.
//
// R4 change: the old gbar used __threadfence() (agent fence -> L2 wbinv on
// every half-step) to publish ~256KB/step of cross-WG data. That re-fetched
// the whole 3MB weight set through the fabric every step (FETCH_SIZE 772MB
// = 512 x 1.5MB) and made every post-barrier load L2-cold. Now the cross-WG
// buffers (ZH, hbf) use agent-scope relaxed atomic loads/stores (sc0 sc1:
// write-through / read-bypass to the MALL coherence point) and the fences
// are gone -- weights stay L2-resident across all 512 steps.

#define T_LEN 512
#define BATCH 64
#define DIN   512
#define DH    512
#define DT    128
#define G_WGS 32

typedef __attribute__((ext_vector_type(8))) short short8;
typedef __attribute__((ext_vector_type(4))) float f32x4;

static __device__ __forceinline__ float bf2f(unsigned short u) {
  unsigned v = ((unsigned)u) << 16;
  return __builtin_bit_cast(float, v);
}
static __device__ __forceinline__ unsigned short f2bf(float f) {
  unsigned v = __builtin_bit_cast(unsigned, f);
  unsigned r = (v + 0x7fffu + ((v >> 16) & 1u)) >> 16;
  return (unsigned short)r;
}
static __device__ __forceinline__ float sigmoid_f(float x) {
  return 1.f / (1.f + __expf(-x));
}
static __device__ __forceinline__ float tanh_f(float x) {
  float e = __expf(-2.f * fabsf(x));
  float t = (1.f - e) / (1.f + e);
  return copysignf(t, x);
}

// ---- cross-XCD bypass accessors (agent scope => sc0 sc1, no L2 residency) --
static __device__ __forceinline__ void bstore_u16(unsigned short* p, unsigned short v) {
  __hip_atomic_store(p, v, __ATOMIC_RELAXED, __HIP_MEMORY_SCOPE_AGENT);
}
// 16B MFMA fragment as two 8B bypass loads (16B-aligned addresses only).
static __device__ __forceinline__ short8 bload_frag(const unsigned short* p) {
  union { short8 s; unsigned long long u[2]; } r;
  r.u[0] = __hip_atomic_load((const unsigned long long*)p,
                             __ATOMIC_RELAXED, __HIP_MEMORY_SCOPE_AGENT);
  r.u[1] = __hip_atomic_load(((const unsigned long long*)p) + 1,
                             __ATOMIC_RELAXED, __HIP_MEMORY_SCOPE_AGENT);
  return r.s;
}

template<bool F32>
static __device__ __forceinline__ void load8(const void* p, size_t off, unsigned short* d) {
  if (F32) {
    const float4* q = (const float4*)((const float*)p + off);
    float4 a = q[0], b = q[1];
    d[0] = f2bf(a.x); d[1] = f2bf(a.y); d[2] = f2bf(a.z); d[3] = f2bf(a.w);
    d[4] = f2bf(b.x); d[5] = f2bf(b.y); d[6] = f2bf(b.z); d[7] = f2bf(b.w);
  } else {
    *(uint4*)d = *(const uint4*)((const unsigned short*)p + off);
  }
}

// ---------------------------------------------------------------------------
// k_tr: dst[n][k] (bf16) = src[k][n] (f32); K,N multiples of 32. LDS-tiled.
// ---------------------------------------------------------------------------
__global__ __launch_bounds__(256) void k_tr(const float* __restrict__ src,
                                            unsigned short* __restrict__ dst,
                                            int K, int N) {
  __shared__ float t[32][33];
  const int tx = threadIdx.x & 31, ty = threadIdx.x >> 5;  // 32 x 8
  const int k0 = blockIdx.y * 32, n0 = blockIdx.x * 32;
  for (int i = ty; i < 32; i += 8)
    t[i][tx] = src[(size_t)(k0 + i) * N + n0 + tx];
  __syncthreads();
  for (int i = ty; i < 32; i += 8)
    dst[(size_t)(n0 + i) * K + k0 + tx] = f2bf(t[tx][i]);
}

// ---------------------------------------------------------------------------
// k_topic: the four topic@W projections, all f32.
// ---------------------------------------------------------------------------
__global__ __launch_bounds__(256) void k_topic(
    const float* __restrict__ topic,
    const float* __restrict__ Wzx,  // [128][1024]
    const float* __restrict__ Wzh,  // [128][1024]
    const float* __restrict__ Whx,  // [128][512]
    const float* __restrict__ Whh,  // [128][512]
    float* __restrict__ tzx, float* __restrict__ tzh,
    float* __restrict__ thx, float* __restrict__ thh)
{
  const int b = blockIdx.x;
  __shared__ float tp[DT];
  if (threadIdx.x < DT) tp[threadIdx.x] = topic[b * DT + threadIdx.x];
  __syncthreads();
  for (int c = threadIdx.x; c < 3072; c += 256) {
    const float* wp; float* op; int ld, cc;
    if (c < 1024)      { wp = Wzx; ld = 1024; cc = c;        op = &tzx[b*1024 + cc]; }
    else if (c < 2048) { wp = Wzh; ld = 1024; cc = c - 1024; op = &tzh[b*1024 + cc]; }
    else if (c < 2560) { wp = Whx; ld = 512;  cc = c - 2048; op = &thx[b*512  + cc]; }
    else               { wp = Whh; ld = 512;  cc = c - 2560; op = &thh[b*512  + cc]; }
    float acc = 0.f;
    #pragma unroll 4
    for (int k = 0; k < DT; ++k) acc += tp[k] * wp[(size_t)k * ld + cc];
    *op = acc;
  }
}

// ---------------------------------------------------------------------------
// gemm64 (phase 1 only): C(bf16) = A @ B, 64x64 tile, LDS-staged.
// EPI==0: C *= rs[(row&63)*ldrs+col]; EPI==1: C += bias[col].
// ---------------------------------------------------------------------------
template<int EPI, bool AF32, bool BF32>
__global__ __launch_bounds__(256) void gemm64(
    const void* __restrict__ A, int lda,
    const void* __restrict__ B1, int ldb1,
    const float* __restrict__ rs1, int ldrs1,
    const float* __restrict__ bias,
    unsigned short* __restrict__ C, int ldc, int K)
{
  __shared__ unsigned short As[64][48];
  __shared__ unsigned short Bs[64][48];
  const int tid = threadIdx.x;
  const int n0 = blockIdx.x * 64;
  const int m0 = blockIdx.y * 64;
  const int wv = tid >> 6, lane = tid & 63;
  const int lh = lane & 15, q8 = (lane >> 4) * 8;
  const int arow = tid >> 2, acol = (tid & 3) * 8;
  const int brow = tid >> 3, bcol = (tid & 7) * 8;
  f32x4 acc[4] = {{0,0,0,0},{0,0,0,0},{0,0,0,0},{0,0,0,0}};

  for (int k0 = 0; k0 < K; k0 += 32) {
    unsigned short av[8], bv[8];
    load8<AF32>(A, (size_t)(m0 + arow) * lda + (k0 + acol), av);
    load8<BF32>(B1, (size_t)(k0 + brow) * ldb1 + (n0 + bcol), bv);
    __syncthreads();
    *(uint4*)(&As[arow][acol]) = *(const uint4*)av;
    #pragma unroll
    for (int i = 0; i < 8; ++i) Bs[bcol + i][brow] = bv[i];
    __syncthreads();
    short8 af = *(const short8*)(&As[wv * 16 + lh][q8]);
    #pragma unroll
    for (int nt = 0; nt < 4; ++nt) {
      short8 bf = *(const short8*)(&Bs[nt * 16 + lh][q8]);
      acc[nt] = __builtin_amdgcn_mfma_f32_16x16x32_bf16(af, bf, acc[nt], 0, 0, 0);
    }
  }

  #pragma unroll
  for (int nt = 0; nt < 4; ++nt) {
    #pragma unroll
    for (int r = 0; r < 4; ++r) {
      int row = m0 + wv * 16 + (lane >> 4) * 4 + r;
      int colc = nt * 16 + lh;
      float v = acc[nt][r];
      if (EPI == 0) v *= rs1[(size_t)(row & 63) * ldrs1 + (n0 + colc)];
      else          v += bias[n0 + colc];
      C[(size_t)row * ldc + (n0 + colc)] = f2bf(v);
    }
  }
}

// ---------------------------------------------------------------------------
// grid barrier: monotone-epoch counter, agent-scope atomics. NO fences --
// cross-WG data moves via sc0/sc1 bypass accessors; each wave drains its
// own vmcnt before the barrier, so bypass stores are at the MALL before
// thread 0 posts the arrival.
// ---------------------------------------------------------------------------
static __device__ __forceinline__ void gbar(int* bar, int target) {
  asm volatile("s_waitcnt vmcnt(0)" ::: "memory");  // my stores are at MALL
  __syncthreads();                                  // ... and so are everyone's
  if (threadIdx.x == 0) {
    __hip_atomic_fetch_add(bar, 1, __ATOMIC_RELAXED, __HIP_MEMORY_SCOPE_AGENT);
    while (__hip_atomic_load(bar, __ATOMIC_RELAXED, __HIP_MEMORY_SCOPE_AGENT) < target)
      __builtin_amdgcn_s_sleep(1);
  }
  __syncthreads();
}

// ---------------------------------------------------------------------------
// k_scan: persistent 512-step GRU scan. Grid = G_WGS x 256.
// Stage A: ZH[b][c] = (hbf @ WaT^T)[b][c] * scale,  c-slice 48 cols per WG.
// Stage B+C: 16 cols x 3 matrices per WG, fused gates; WG owns its h columns.
// Fragment layouts (m89-verified): A[m=lane&15][k=quad*8+j] from row-major,
// B[n=lane&15][k=quad*8+j] from [n][k]-transposed weights, C/D col=lane&15,
// row=quad*4+reg.
// Cross-WG rw buffers (ZH, hbf): agent-scope bypass only. Weights/streams:
// plain cached loads (L2-resident across steps).
// ---------------------------------------------------------------------------
__global__ __launch_bounds__(256) void k_scan(
    const unsigned short* __restrict__ WaT,   // [1536][512] bf16 ([W_h2zr|W_h2h]^T)
    const unsigned short* __restrict__ WbT,   // [1536][512] bf16 (z|r|v stacked ^T)
    const float* __restrict__ tzh,            // [64][1024]
    const float* __restrict__ thh,            // [64][512]
    const unsigned short* __restrict__ ZRx,   // [T*64][1024] bf16
    const unsigned short* __restrict__ Hx,    // [T*64][512] bf16
    const float* __restrict__ mask,           // [T*64]
    unsigned short* ZH,                       // [64][1536] bf16 (rw, cross-WG)
    float* Hst,                               // [64][512] f32 master h
    unsigned short* hbf,                      // [64][512] bf16 (rw, cross-WG)
    float* out, int* bar)
{
  const int wg = blockIdx.x;
  const int tid = threadIdx.x;
  const int wv = tid >> 6, lane = tid & 63;
  const int lh = lane & 15, quad = lane >> 4;
  const int q8 = quad * 8;
  const int rowA = wv * 16 + lh;     // A-fragment row (batch)
  int ep = 0;

  for (int t = 0; t < T_LEN; ++t) {
    // ---- stage A ----
    f32x4 a0 = {0,0,0,0}, a1 = {0,0,0,0}, a2 = {0,0,0,0};
    #pragma unroll 8
    for (int k0 = 0; k0 < 512; k0 += 32) {
      short8 af = bload_frag(hbf + rowA * 512 + k0 + q8);
      short8 b0 = *(const short8*)(WaT + (size_t)(wg*48 +  0 + lh) * 512 + k0 + q8);
      short8 b1 = *(const short8*)(WaT + (size_t)(wg*48 + 16 + lh) * 512 + k0 + q8);
      short8 b2 = *(const short8*)(WaT + (size_t)(wg*48 + 32 + lh) * 512 + k0 + q8);
      a0 = __builtin_amdgcn_mfma_f32_16x16x32_bf16(af, b0, a0, 0, 0, 0);
      a1 = __builtin_amdgcn_mfma_f32_16x16x32_bf16(af, b1, a1, 0, 0, 0);
      a2 = __builtin_amdgcn_mfma_f32_16x16x32_bf16(af, b2, a2, 0, 0, 0);
    }
    {
      f32x4 av[3] = {a0, a1, a2};
      #pragma unroll
      for (int nt = 0; nt < 3; ++nt) {
        #pragma unroll
        for (int r = 0; r < 4; ++r) {
          int b = wv * 16 + quad * 4 + r;
          int c = wg * 48 + nt * 16 + lh;
          float sc = (c < 1024) ? tzh[b * 1024 + c] : thh[b * 512 + (c - 1024)];
          bstore_u16(&ZH[b * 1536 + c], f2bf(av[nt][r] * sc));
        }
      }
    }
    ++ep; gbar(bar, ep * G_WGS);

    // ---- stage B + C ----
    f32x4 bz = {0,0,0,0}, br = {0,0,0,0}, bv = {0,0,0,0};
    #pragma unroll 8
    for (int k0 = 0; k0 < 512; k0 += 32) {
      const unsigned short* zrow = ZH + rowA * 1536;
      short8 az = bload_frag(zrow + k0 + q8);
      short8 ar = bload_frag(zrow + 512 + k0 + q8);
      short8 au = bload_frag(zrow + 1024 + k0 + q8);
      short8 wz = *(const short8*)(WbT + (size_t)(       wg*16 + lh) * 512 + k0 + q8);
      short8 wr = *(const short8*)(WbT + (size_t)(512  + wg*16 + lh) * 512 + k0 + q8);
      short8 wu = *(const short8*)(WbT + (size_t)(1024 + wg*16 + lh) * 512 + k0 + q8);
      bz = __builtin_amdgcn_mfma_f32_16x16x32_bf16(az, wz, bz, 0, 0, 0);
      br = __builtin_amdgcn_mfma_f32_16x16x32_bf16(ar, wr, br, 0, 0, 0);
      bv = __builtin_amdgcn_mfma_f32_16x16x32_bf16(au, wu, bv, 0, 0, 0);
    }
    #pragma unroll
    for (int r = 0; r < 4; ++r) {
      int b = wv * 16 + quad * 4 + r;
      int d = wg * 16 + lh;
      size_t itb = (size_t)t * BATCH + b;
      float pz = bz[r] + bf2f(ZRx[itb * 1024 + d]);
      float pr = br[r] + bf2f(ZRx[itb * 1024 + 512 + d]);
      float z  = sigmoid_f(pz);
      float rr = sigmoid_f(pr);
      float hv = tanh_f(bf2f(Hx[itb * 512 + d]) + rr * bv[r]);
      float hold = Hst[b * 512 + d];
      float m = mask[itb];
      float hnew = (1.f - z) * hv + z * hold;
      hnew = m * hnew + (1.f - m) * hold;
      Hst[b * 512 + d] = hnew;
      bstore_u16(&hbf[b * 512 + d], f2bf(hnew));
      out[itb * 512 + d] = hnew;
      if (t == T_LEN - 1) out[(size_t)T_LEN * BATCH * DH + (size_t)b * 512 + d] = hnew;
    }
    ++ep; gbar(bar, ep * G_WGS);
  }
}

// ---------------------------------------------------------------------------
extern "C" void kernel_launch(void* const* d_in, const int* in_sizes, int n_in,
                              void* d_out, int out_size, void* d_ws, size_t ws_size,
                              hipStream_t stream) {
  (void)in_sizes; (void)n_in; (void)out_size; (void)ws_size;
  const float* x        = (const float*)d_in[0];
  const float* topic    = (const float*)d_in[1];
  const float* mask     = (const float*)d_in[2];
  const float* W_x2zr   = (const float*)d_in[3];
  const float* W_tp2zrx = (const float*)d_in[4];
  const float* W_xtp2z  = (const float*)d_in[5];
  const float* b_xtp2z  = (const float*)d_in[6];
  const float* W_xtp2r  = (const float*)d_in[7];
  const float* b_xtp2r  = (const float*)d_in[8];
  const float* W_h2zr   = (const float*)d_in[9];
  const float* W_tp2zrh = (const float*)d_in[10];
  const float* W_htp2z  = (const float*)d_in[11];
  const float* W_htp2r  = (const float*)d_in[12];
  const float* W_x2h    = (const float*)d_in[13];
  const float* W_tp2hx  = (const float*)d_in[14];
  const float* W_xtp2h  = (const float*)d_in[15];
  const float* b_xtp2h  = (const float*)d_in[16];
  const float* W_h2h    = (const float*)d_in[17];
  const float* W_tp2hh  = (const float*)d_in[18];
  const float* W_htp2h  = (const float*)d_in[19];
  float* out = (float*)d_out;

  // ---- workspace carve ----
  char* w = (char*)d_ws;
  int*            bar  = (int*)w;            w += 128;                        // barrier ctr
  float*          Hst  = (float*)w;          w += (size_t)BATCH * 512 * 4;    // 128 KB
  unsigned short* hbf  = (unsigned short*)w; w += (size_t)BATCH * 512 * 2;    // 64 KB
  // ^ [bar|Hst|hbf] contiguous: one memset zeroes all three.
  float* tzx = (float*)w;           w += (size_t)BATCH * 1024 * 4;
  float* tzh = (float*)w;           w += (size_t)BATCH * 1024 * 4;
  float* thx = (float*)w;           w += (size_t)BATCH * 512 * 4;
  float* thh = (float*)w;           w += (size_t)BATCH * 512 * 4;
  unsigned short* WaT = (unsigned short*)w;  w += (size_t)1536 * 512 * 2;     // 1.5 MB
  unsigned short* WbT = (unsigned short*)w;  w += (size_t)1536 * 512 * 2;     // 1.5 MB
  unsigned short* ZH  = (unsigned short*)w;  w += (size_t)BATCH * 1536 * 2;   // 192 KB
  unsigned short* ZRs   = (unsigned short*)w; w += (size_t)T_LEN * BATCH * 1024 * 2; // 64 MB
  unsigned short* ZRxtp = (unsigned short*)w; w += (size_t)T_LEN * BATCH * 1024 * 2; // 64 MB
  unsigned short* Xhs  = ZRs;                              // aliases (stream-ordered)
  unsigned short* Hxtp = ZRs + (size_t)T_LEN * BATCH * 512;

  const int M = T_LEN * BATCH;  // 32768

  hipMemsetAsync(bar, 0, 128 + (size_t)BATCH * 512 * 4 + (size_t)BATCH * 512 * 2, stream);

  // ---- weight transposes -> bf16 [n][k] ----
  k_tr<<<dim3(1024/32, 512/32), 256, 0, stream>>>(W_h2zr,  WaT,               512, 1024);
  k_tr<<<dim3( 512/32, 512/32), 256, 0, stream>>>(W_h2h,   WaT + 1024 * 512,  512,  512);
  k_tr<<<dim3( 512/32, 512/32), 256, 0, stream>>>(W_htp2z, WbT,               512,  512);
  k_tr<<<dim3( 512/32, 512/32), 256, 0, stream>>>(W_htp2r, WbT +  512 * 512,  512,  512);
  k_tr<<<dim3( 512/32, 512/32), 256, 0, stream>>>(W_htp2h, WbT + 1024 * 512,  512,  512);

  // ---- phase 1 ----
  k_topic<<<BATCH, 256, 0, stream>>>(topic, W_tp2zrx, W_tp2zrh, W_tp2hx, W_tp2hh,
                                     tzx, tzh, thx, thh);
  gemm64<0, true, true><<<dim3(1024/64, M/64), 256, 0, stream>>>(
      x, DIN, W_x2zr, 1024, tzx, 1024, nullptr, ZRs, 1024, DIN);
  gemm64<1, false, true><<<dim3(512/64, M/64), 256, 0, stream>>>(
      ZRs, 1024, W_xtp2z, 512, nullptr, 0, b_xtp2z, ZRxtp, 1024, 512);
  gemm64<1, false, true><<<dim3(512/64, M/64), 256, 0, stream>>>(
      ZRs + 512, 1024, W_xtp2r, 512, nullptr, 0, b_xtp2r, ZRxtp + 512, 1024, 512);
  gemm64<0, true, true><<<dim3(512/64, M/64), 256, 0, stream>>>(
      x, DIN, W_x2h, 512, thx, 512, nullptr, Xhs, 512, DIN);
  gemm64<1, false, true><<<dim3(512/64, M/64), 256, 0, stream>>>(
      Xhs, 512, W_xtp2h, 512, nullptr, 0, b_xtp2h, Hxtp, 512, 512);

  // ---- phase 2: persistent scan ----
  k_scan<<<G_WGS, 256, 0, stream>>>(WaT, WbT, tzh, thh, ZRxtp, Hxtp, mask,
                                    ZH, Hst, hbf, out, bar);
}

// Round 2
// 8395.636 us; speedup vs baseline: 2.0198x; 1.9272x over previous
//
#include <hip/hip_runtime.h>
#include <stdint.h>
#include <stddef.h>

// TPGRUCell forward, MI355X gfx950.
// R5 restructure: fold the per-batch diagonal topic scales into precomputed
// combined recurrent matrices  Az_b = W_h2zr[:,:512] diag(tzh_b[:512]) W_htp2z,
// Ar_b likewise, Ah_b = W_h2h diag(thh_b) W_htp2h.  The 512-step recurrence
// then needs only per-batch GEMVs (h_b @ A*_b) -> batches are INDEPENDENT.
// The old 32-WG global barrier + ZH all-to-all (latency-bound, 30us/step)
// is replaced by 64 independent 4-WG groups, one tiny barrier per step,
// streaming a MALL-resident 96 MiB matrix set.

#define T_LEN 512
#define BATCH 64
#define DIN   512
#define DH    512
#define DT    128

typedef __attribute__((ext_vector_type(8))) short short8;
typedef __attribute__((ext_vector_type(4))) float f32x4;

static __device__ __forceinline__ float bf2f(unsigned short u) {
  unsigned v = ((unsigned)u) << 16;
  return __builtin_bit_cast(float, v);
}
static __device__ __forceinline__ unsigned short f2bf(float f) {
  unsigned v = __builtin_bit_cast(unsigned, f);
  unsigned r = (v + 0x7fffu + ((v >> 16) & 1u)) >> 16;
  return (unsigned short)r;
}
static __device__ __forceinline__ float sigmoid_f(float x) {
  return 1.f / (1.f + __expf(-x));
}
static __device__ __forceinline__ float tanh_f(float x) {
  float e = __expf(-2.f * fabsf(x));
  float t = (1.f - e) / (1.f + e);
  return copysignf(t, x);
}

// cross-XCD bypass store (agent scope => write-through to MALL)
static __device__ __forceinline__ void bstore_u16(unsigned short* p, unsigned short v) {
  __hip_atomic_store(p, v, __ATOMIC_RELAXED, __HIP_MEMORY_SCOPE_AGENT);
}

template<bool F32>
static __device__ __forceinline__ void load8(const void* p, size_t off, unsigned short* d) {
  if (F32) {
    const float4* q = (const float4*)((const float*)p + off);
    float4 a = q[0], b = q[1];
    d[0] = f2bf(a.x); d[1] = f2bf(a.y); d[2] = f2bf(a.z); d[3] = f2bf(a.w);
    d[4] = f2bf(b.x); d[5] = f2bf(b.y); d[6] = f2bf(b.z); d[7] = f2bf(b.w);
  } else {
    *(uint4*)d = *(const uint4*)((const unsigned short*)p + off);
  }
}

// ---------------------------------------------------------------------------
// k_topic: the four topic@W projections, all f32.
// ---------------------------------------------------------------------------
__global__ __launch_bounds__(256) void k_topic(
    const float* __restrict__ topic,
    const float* __restrict__ Wzx,  // [128][1024]
    const float* __restrict__ Wzh,  // [128][1024]
    const float* __restrict__ Whx,  // [128][512]
    const float* __restrict__ Whh,  // [128][512]
    float* __restrict__ tzx, float* __restrict__ tzh,
    float* __restrict__ thx, float* __restrict__ thh)
{
  const int b = blockIdx.x;
  __shared__ float tp[DT];
  if (threadIdx.x < DT) tp[threadIdx.x] = topic[b * DT + threadIdx.x];
  __syncthreads();
  for (int c = threadIdx.x; c < 3072; c += 256) {
    const float* wp; float* op; int ld, cc;
    if (c < 1024)      { wp = Wzx; ld = 1024; cc = c;        op = &tzx[b*1024 + cc]; }
    else if (c < 2048) { wp = Wzh; ld = 1024; cc = c - 1024; op = &tzh[b*1024 + cc]; }
    else if (c < 2560) { wp = Whx; ld = 512;  cc = c - 2048; op = &thx[b*512  + cc]; }
    else               { wp = Whh; ld = 512;  cc = c - 2560; op = &thh[b*512  + cc]; }
    float acc = 0.f;
    #pragma unroll 4
    for (int k = 0; k < DT; ++k) acc += tp[k] * wp[(size_t)k * ld + cc];
    *op = acc;
  }
}

// ---------------------------------------------------------------------------
// gemm64 (phase 1): C(bf16) = A @ B, 64x64 tile, LDS-staged (verified).
// EPI==0: C *= rs[(row&63)*ldrs+col]; EPI==1: C += bias[col].
// ---------------------------------------------------------------------------
template<int EPI, bool AF32, bool BF32>
__global__ __launch_bounds__(256) void gemm64(
    const void* __restrict__ A, int lda,
    const void* __restrict__ B1, int ldb1,
    const float* __restrict__ rs1, int ldrs1,
    const float* __restrict__ bias,
    unsigned short* __restrict__ C, int ldc, int K)
{
  __shared__ unsigned short As[64][48];
  __shared__ unsigned short Bs[64][48];
  const int tid = threadIdx.x;
  const int n0 = blockIdx.x * 64;
  const int m0 = blockIdx.y * 64;
  const int wv = tid >> 6, lane = tid & 63;
  const int lh = lane & 15, q8 = (lane >> 4) * 8;
  const int arow = tid >> 2, acol = (tid & 3) * 8;
  const int brow = tid >> 3, bcol = (tid & 7) * 8;
  f32x4 acc[4] = {{0,0,0,0},{0,0,0,0},{0,0,0,0},{0,0,0,0}};

  for (int k0 = 0; k0 < K; k0 += 32) {
    unsigned short av[8], bv[8];
    load8<AF32>(A, (size_t)(m0 + arow) * lda + (k0 + acol), av);
    load8<BF32>(B1, (size_t)(k0 + brow) * ldb1 + (n0 + bcol), bv);
    __syncthreads();
    *(uint4*)(&As[arow][acol]) = *(const uint4*)av;
    #pragma unroll
    for (int i = 0; i < 8; ++i) Bs[bcol + i][brow] = bv[i];
    __syncthreads();
    short8 af = *(const short8*)(&As[wv * 16 + lh][q8]);
    #pragma unroll
    for (int nt = 0; nt < 4; ++nt) {
      short8 bf = *(const short8*)(&Bs[nt * 16 + lh][q8]);
      acc[nt] = __builtin_amdgcn_mfma_f32_16x16x32_bf16(af, bf, acc[nt], 0, 0, 0);
    }
  }

  #pragma unroll
  for (int nt = 0; nt < 4; ++nt) {
    #pragma unroll
    for (int r = 0; r < 4; ++r) {
      int row = m0 + wv * 16 + (lane >> 4) * 4 + r;
      int colc = nt * 16 + lh;
      float v = acc[nt][r];
      if (EPI == 0) v *= rs1[(size_t)(row & 63) * ldrs1 + (n0 + colc)];
      else          v += bias[n0 + colc];
      C[(size_t)row * ldc + (n0 + colc)] = f2bf(v);
    }
  }
}

// ---------------------------------------------------------------------------
// k_comb: per-batch combined matrix  C_b[i][c] = sum_k W1[i][off1+k] *
//         S[b][offS+k] * W2[k][c].   Grid (8, 8, 64), 256 thr, K = 512.
// Same LDS/fragment scheme as gemm64 (verified layouts).
// ---------------------------------------------------------------------------
__global__ __launch_bounds__(256) void k_comb(
    const float* __restrict__ W1, int ld1, int off1,  // [512][ld1]
    const float* __restrict__ W2,                     // [512][512]
    const float* __restrict__ S, int ldS, int offS,   // [64][ldS]
    unsigned short* __restrict__ Cout)                // [64][512][512] bf16
{
  __shared__ unsigned short As[64][48];
  __shared__ unsigned short Bs[64][48];
  const int tid = threadIdx.x;
  const int n0 = blockIdx.x * 64;
  const int m0 = blockIdx.y * 64;
  const int b  = blockIdx.z;
  const int wv = tid >> 6, lane = tid & 63;
  const int lh = lane & 15, q8 = (lane >> 4) * 8;
  const int arow = tid >> 2, acol = (tid & 3) * 8;
  const int brow = tid >> 3, bcol = (tid & 7) * 8;
  const float* sv = S + (size_t)b * ldS + offS;
  f32x4 acc[4] = {{0,0,0,0},{0,0,0,0},{0,0,0,0},{0,0,0,0}};

  for (int k0 = 0; k0 < 512; k0 += 32) {
    unsigned short av[8], bv[8];
    {
      const float* p = W1 + (size_t)(m0 + arow) * ld1 + off1 + k0 + acol;
      float4 a = ((const float4*)p)[0], c2 = ((const float4*)p)[1];
      av[0]=f2bf(a.x); av[1]=f2bf(a.y); av[2]=f2bf(a.z); av[3]=f2bf(a.w);
      av[4]=f2bf(c2.x); av[5]=f2bf(c2.y); av[6]=f2bf(c2.z); av[7]=f2bf(c2.w);
    }
    {
      float sk = sv[k0 + brow];
      const float* p = W2 + (size_t)(k0 + brow) * 512 + n0 + bcol;
      float4 a = ((const float4*)p)[0], c2 = ((const float4*)p)[1];
      bv[0]=f2bf(a.x*sk); bv[1]=f2bf(a.y*sk); bv[2]=f2bf(a.z*sk); bv[3]=f2bf(a.w*sk);
      bv[4]=f2bf(c2.x*sk); bv[5]=f2bf(c2.y*sk); bv[6]=f2bf(c2.z*sk); bv[7]=f2bf(c2.w*sk);
    }
    __syncthreads();
    *(uint4*)(&As[arow][acol]) = *(const uint4*)av;
    #pragma unroll
    for (int i = 0; i < 8; ++i) Bs[bcol + i][brow] = bv[i];
    __syncthreads();
    short8 af = *(const short8*)(&As[wv * 16 + lh][q8]);
    #pragma unroll
    for (int nt = 0; nt < 4; ++nt) {
      short8 bf = *(const short8*)(&Bs[nt * 16 + lh][q8]);
      acc[nt] = __builtin_amdgcn_mfma_f32_16x16x32_bf16(af, bf, acc[nt], 0, 0, 0);
    }
  }

  #pragma unroll
  for (int nt = 0; nt < 4; ++nt) {
    #pragma unroll
    for (int r = 0; r < 4; ++r) {
      int row = m0 + wv * 16 + (lane >> 4) * 4 + r;
      int col = n0 + nt * 16 + lh;
      Cout[(size_t)b * 262144 + (size_t)row * 512 + col] = f2bf(acc[nt][r]);
    }
  }
}

// ---------------------------------------------------------------------------
// group barrier: monotone-epoch counter, agent-scope atomics, no fences.
// Each thread drains its own vmcnt before the WG barrier, so all bypass
// stores are MALL-visible before thread 0 posts arrival (R4-verified pattern).
// ---------------------------------------------------------------------------
static __device__ __forceinline__ void gbar(int* bar, int target) {
  asm volatile("s_waitcnt vmcnt(0)" ::: "memory");
  __syncthreads();
  if (threadIdx.x == 0) {
    __hip_atomic_fetch_add(bar, 1, __ATOMIC_RELAXED, __HIP_MEMORY_SCOPE_AGENT);
    while (__hip_atomic_load(bar, __ATOMIC_RELAXED, __HIP_MEMORY_SCOPE_AGENT) < target)
      __builtin_amdgcn_s_sleep(1);
  }
  __syncthreads();
}

static __device__ __forceinline__ void accum8(float* a, float hk, uint4 v) {
  unsigned u0 = v.x, u1 = v.y, u2 = v.z, u3 = v.w;
  a[0] += hk * __builtin_bit_cast(float, u0 << 16);
  a[1] += hk * __builtin_bit_cast(float, u0 & 0xffff0000u);
  a[2] += hk * __builtin_bit_cast(float, u1 << 16);
  a[3] += hk * __builtin_bit_cast(float, u1 & 0xffff0000u);
  a[4] += hk * __builtin_bit_cast(float, u2 << 16);
  a[5] += hk * __builtin_bit_cast(float, u2 & 0xffff0000u);
  a[6] += hk * __builtin_bit_cast(float, u3 << 16);
  a[7] += hk * __builtin_bit_cast(float, u3 & 0xffff0000u);
}

// ---------------------------------------------------------------------------
// k_scan2: 512-step scan via per-batch GEMV on combined matrices.
// Grid = 256 WGs x 512 thr. WG g: batch b = g>>2, column quarter q = g&3
// (cols [q*128, q*128+128)).  Thread t: chunk = t&15 (col octet), ph = t>>4
// (k = ph + 32j).  One 4-WG barrier per step; h exchanged via double-buffered
// bypass buffer; master h (f32) lives in gate-thread registers.
// ---------------------------------------------------------------------------
__global__ __launch_bounds__(512) void k_scan2(
    const unsigned short* __restrict__ Az,   // [64][512][512] bf16
    const unsigned short* __restrict__ Ar,
    const unsigned short* __restrict__ Ah,
    const unsigned short* __restrict__ ZRx,  // [T*64][1024] bf16
    const unsigned short* __restrict__ Hx,   // [T*64][512] bf16
    const float* __restrict__ mask,          // [T*64]
    unsigned short* hbuf,                    // [2][64][512] bf16 (rw, cross-WG)
    float* out, int* bar)
{
  const int g = blockIdx.x;
  const int b = g >> 2;
  const int q = g & 3;
  const int c0 = q * 128;
  const int t = threadIdx.x;
  const int chunk = t & 15;
  const int ph = t >> 4;
  __shared__ float hs[512];
  __shared__ float part[32][16][25];   // [ph][chunk][3*8], padded stride 25
  int* mybar = bar + b * 32;           // 128B-separated counters

  const size_t mbase = (size_t)b * 262144 + (size_t)ph * 512 + c0 + chunk * 8;
  const unsigned short* pz0 = Az + mbase;
  const unsigned short* pr0 = Ar + mbase;
  const unsigned short* pv0 = Ah + mbase;

  float hold = 0.f;  // master h (f32) for col c0+t, threads t<128
  int ep = 0;

  for (int tm = 0; tm < T_LEN; ++tm) {
    const int cur = tm & 1;
    const size_t itb = (size_t)tm * BATCH + b;
    // prefetch gate operands (latency hidden under GEMV)
    float g_zx = 0.f, g_rx = 0.f, g_hx = 0.f, g_m = 0.f;
    if (t < 128) {
      int gc = c0 + t;
      g_zx = bf2f(ZRx[itb * 1024 + gc]);
      g_rx = bf2f(ZRx[itb * 1024 + 512 + gc]);
      g_hx = bf2f(Hx[itb * 512 + gc]);
      g_m  = mask[itb];
    }
    // full h -> LDS (bypass read; bf16 -> f32)
    if (t < 256) {
      unsigned v = __hip_atomic_load(
          (const unsigned*)(hbuf + ((size_t)cur * 64 + b) * 512) + t,
          __ATOMIC_RELAXED, __HIP_MEMORY_SCOPE_AGENT);
      hs[2 * t]     = bf2f((unsigned short)(v & 0xffffu));
      hs[2 * t + 1] = bf2f((unsigned short)(v >> 16));
    }
    __syncthreads();

    // GEMV partials: 16 k's per thread, 8 cols, 3 matrices
    float az[8] = {0,0,0,0,0,0,0,0};
    float ar[8] = {0,0,0,0,0,0,0,0};
    float av[8] = {0,0,0,0,0,0,0,0};
    #pragma unroll 4
    for (int j = 0; j < 16; ++j) {
      float hk = hs[ph + 32 * j];
      uint4 vz = *(const uint4*)(pz0 + (size_t)j * 32 * 512);
      uint4 vr = *(const uint4*)(pr0 + (size_t)j * 32 * 512);
      uint4 vv = *(const uint4*)(pv0 + (size_t)j * 32 * 512);
      accum8(az, hk, vz);
      accum8(ar, hk, vr);
      accum8(av, hk, vv);
    }
    #pragma unroll
    for (int e = 0; e < 8; ++e) {
      part[ph][chunk][e]      = az[e];
      part[ph][chunk][8 + e]  = ar[e];
      part[ph][chunk][16 + e] = av[e];
    }
    __syncthreads();

    // gates: threads 0..127 own one column each
    if (t < 128) {
      int gc = c0 + t;
      int ch = t >> 3, e = t & 7;
      float sz = 0.f, sr = 0.f, sh = 0.f;
      #pragma unroll 8
      for (int p = 0; p < 32; ++p) {
        sz += part[p][ch][e];
        sr += part[p][ch][8 + e];
        sh += part[p][ch][16 + e];
      }
      float z  = sigmoid_f(sz + g_zx);
      float r  = sigmoid_f(sr + g_rx);
      float hv = tanh_f(g_hx + r * sh);
      float hnew = (1.f - z) * hv + z * hold;
      hnew = g_m * hnew + (1.f - g_m) * hold;
      hold = hnew;
      out[itb * 512 + gc] = hnew;
      if (tm == T_LEN - 1)
        out[(size_t)T_LEN * BATCH * 512 + (size_t)b * 512 + gc] = hnew;
      bstore_u16(hbuf + ((size_t)(cur ^ 1) * 64 + b) * 512 + gc, f2bf(hnew));
    }
    ++ep;
    gbar(mybar, 4 * ep);
  }
}

// ---------------------------------------------------------------------------
extern "C" void kernel_launch(void* const* d_in, const int* in_sizes, int n_in,
                              void* d_out, int out_size, void* d_ws, size_t ws_size,
                              hipStream_t stream) {
  (void)in_sizes; (void)n_in; (void)out_size; (void)ws_size;
  const float* x        = (const float*)d_in[0];
  const float* topic    = (const float*)d_in[1];
  const float* mask     = (const float*)d_in[2];
  const float* W_x2zr   = (const float*)d_in[3];
  const float* W_tp2zrx = (const float*)d_in[4];
  const float* W_xtp2z  = (const float*)d_in[5];
  const float* b_xtp2z  = (const float*)d_in[6];
  const float* W_xtp2r  = (const float*)d_in[7];
  const float* b_xtp2r  = (const float*)d_in[8];
  const float* W_h2zr   = (const float*)d_in[9];
  const float* W_tp2zrh = (const float*)d_in[10];
  const float* W_htp2z  = (const float*)d_in[11];
  const float* W_htp2r  = (const float*)d_in[12];
  const float* W_x2h    = (const float*)d_in[13];
  const float* W_tp2hx  = (const float*)d_in[14];
  const float* W_xtp2h  = (const float*)d_in[15];
  const float* b_xtp2h  = (const float*)d_in[16];
  const float* W_h2h    = (const float*)d_in[17];
  const float* W_tp2hh  = (const float*)d_in[18];
  const float* W_htp2h  = (const float*)d_in[19];
  float* out = (float*)d_out;

  // ---- workspace carve (~194 MiB) ----
  char* w = (char*)d_ws;
  int*            bar  = (int*)w;            w += 8192;                       // 64 x 128B counters
  unsigned short* hbuf = (unsigned short*)w; w += (size_t)2 * BATCH * 512 * 2; // 128 KB
  // ^ [bar|hbuf] contiguous: one memset zeroes both.
  float* tzx = (float*)w;           w += (size_t)BATCH * 1024 * 4;
  float* tzh = (float*)w;           w += (size_t)BATCH * 1024 * 4;
  float* thx = (float*)w;           w += (size_t)BATCH * 512 * 4;
  float* thh = (float*)w;           w += (size_t)BATCH * 512 * 4;
  unsigned short* ZRxtp = (unsigned short*)w; w += (size_t)T_LEN * BATCH * 1024 * 2; // 64 MiB
  unsigned short* Hxtp  = (unsigned short*)w; w += (size_t)T_LEN * BATCH * 512 * 2;  // 32 MiB
  unsigned short* SCR   = (unsigned short*)w; w += (size_t)T_LEN * BATCH * 1024 * 2; // 64 MiB
  unsigned short* AhM   = (unsigned short*)w; w += (size_t)BATCH * 512 * 512 * 2;    // 32 MiB
  // SCR: phase-1 staging (ZRs, then Xhs), afterwards Az|Ar (2 x 32 MiB).
  unsigned short* ZRs = SCR;
  unsigned short* Xhs = SCR;
  unsigned short* AzM = SCR;
  unsigned short* ArM = SCR + (size_t)BATCH * 512 * 512;

  const int M = T_LEN * BATCH;  // 32768

  hipMemsetAsync(bar, 0, 8192 + (size_t)2 * BATCH * 512 * 2, stream);

  // ---- phase 1: topic projections + x-side GEMM chain ----
  k_topic<<<BATCH, 256, 0, stream>>>(topic, W_tp2zrx, W_tp2zrh, W_tp2hx, W_tp2hh,
                                     tzx, tzh, thx, thh);
  gemm64<0, true, true><<<dim3(1024/64, M/64), 256, 0, stream>>>(
      x, DIN, W_x2zr, 1024, tzx, 1024, nullptr, ZRs, 1024, DIN);
  gemm64<1, false, true><<<dim3(512/64, M/64), 256, 0, stream>>>(
      ZRs, 1024, W_xtp2z, 512, nullptr, 0, b_xtp2z, ZRxtp, 1024, 512);
  gemm64<1, false, true><<<dim3(512/64, M/64), 256, 0, stream>>>(
      ZRs + 512, 1024, W_xtp2r, 512, nullptr, 0, b_xtp2r, ZRxtp + 512, 1024, 512);
  gemm64<0, true, true><<<dim3(512/64, M/64), 256, 0, stream>>>(
      x, DIN, W_x2h, 512, thx, 512, nullptr, Xhs, 512, DIN);
  gemm64<1, false, true><<<dim3(512/64, M/64), 256, 0, stream>>>(
      Xhs, 512, W_xtp2h, 512, nullptr, 0, b_xtp2h, Hxtp, 512, 512);

  // ---- combined per-batch recurrent matrices (overwrite SCR after use) ----
  k_comb<<<dim3(8, 8, 64), 256, 0, stream>>>(W_h2zr, 1024,   0, W_htp2z, tzh, 1024,   0, AzM);
  k_comb<<<dim3(8, 8, 64), 256, 0, stream>>>(W_h2zr, 1024, 512, W_htp2r, tzh, 1024, 512, ArM);
  k_comb<<<dim3(8, 8, 64), 256, 0, stream>>>(W_h2h,   512,   0, W_htp2h, thh,  512,   0, AhM);

  // ---- phase 2: per-batch GEMV scan, 64 independent 4-WG groups ----
  k_scan2<<<256, 512, 0, stream>>>(AzM, ArM, AhM, ZRxtp, Hxtp, mask,
                                   hbuf, out, bar);
}

// Round 3
// 4974.999 us; speedup vs baseline: 3.4086x; 1.6876x over previous
//
#include <hip/hip_runtime.h>
#include <stdint.h>
#include <stddef.h>

// TPGRUCell forward, MI355X gfx950.
// R5 restructure: fold the per-batch diagonal topic scales into precomputed
// combined recurrent matrices  Az_b = W_h2zr[:,:512] diag(tzh_b[:512]) W_htp2z,
// Ar_b likewise, Ah_b = W_h2h diag(thh_b) W_htp2h.  The 512-step recurrence
// then needs only per-batch GEMVs (h_b @ A*_b) -> batches are INDEPENDENT.
// R6: the scan is fetch-parallelism-bound (24% occupancy, 3.56 TB/s, VGPR 40).
// Double resident waves (512 WGs x 512 thr = 2 WG/CU, 8 WGs per batch, 64
// cols each) and fully unroll the k-loop (24 outstanding 16B loads/thread).

#define T_LEN 512
#define BATCH 64
#define DIN   512
#define DH    512
#define DT    128

typedef __attribute__((ext_vector_type(8))) short short8;
typedef __attribute__((ext_vector_type(4))) float f32x4;

static __device__ __forceinline__ float bf2f(unsigned short u) {
  unsigned v = ((unsigned)u) << 16;
  return __builtin_bit_cast(float, v);
}
static __device__ __forceinline__ unsigned short f2bf(float f) {
  unsigned v = __builtin_bit_cast(unsigned, f);
  unsigned r = (v + 0x7fffu + ((v >> 16) & 1u)) >> 16;
  return (unsigned short)r;
}
static __device__ __forceinline__ float sigmoid_f(float x) {
  return 1.f / (1.f + __expf(-x));
}
static __device__ __forceinline__ float tanh_f(float x) {
  float e = __expf(-2.f * fabsf(x));
  float t = (1.f - e) / (1.f + e);
  return copysignf(t, x);
}

// cross-XCD bypass store (agent scope => write-through to MALL)
static __device__ __forceinline__ void bstore_u16(unsigned short* p, unsigned short v) {
  __hip_atomic_store(p, v, __ATOMIC_RELAXED, __HIP_MEMORY_SCOPE_AGENT);
}

template<bool F32>
static __device__ __forceinline__ void load8(const void* p, size_t off, unsigned short* d) {
  if (F32) {
    const float4* q = (const float4*)((const float*)p + off);
    float4 a = q[0], b = q[1];
    d[0] = f2bf(a.x); d[1] = f2bf(a.y); d[2] = f2bf(a.z); d[3] = f2bf(a.w);
    d[4] = f2bf(b.x); d[5] = f2bf(b.y); d[6] = f2bf(b.z); d[7] = f2bf(b.w);
  } else {
    *(uint4*)d = *(const uint4*)((const unsigned short*)p + off);
  }
}

// ---------------------------------------------------------------------------
// k_topic: the four topic@W projections, all f32.
// ---------------------------------------------------------------------------
__global__ __launch_bounds__(256) void k_topic(
    const float* __restrict__ topic,
    const float* __restrict__ Wzx,  // [128][1024]
    const float* __restrict__ Wzh,  // [128][1024]
    const float* __restrict__ Whx,  // [128][512]
    const float* __restrict__ Whh,  // [128][512]
    float* __restrict__ tzx, float* __restrict__ tzh,
    float* __restrict__ thx, float* __restrict__ thh)
{
  const int b = blockIdx.x;
  __shared__ float tp[DT];
  if (threadIdx.x < DT) tp[threadIdx.x] = topic[b * DT + threadIdx.x];
  __syncthreads();
  for (int c = threadIdx.x; c < 3072; c += 256) {
    const float* wp; float* op; int ld, cc;
    if (c < 1024)      { wp = Wzx; ld = 1024; cc = c;        op = &tzx[b*1024 + cc]; }
    else if (c < 2048) { wp = Wzh; ld = 1024; cc = c - 1024; op = &tzh[b*1024 + cc]; }
    else if (c < 2560) { wp = Whx; ld = 512;  cc = c - 2048; op = &thx[b*512  + cc]; }
    else               { wp = Whh; ld = 512;  cc = c - 2560; op = &thh[b*512  + cc]; }
    float acc = 0.f;
    #pragma unroll 4
    for (int k = 0; k < DT; ++k) acc += tp[k] * wp[(size_t)k * ld + cc];
    *op = acc;
  }
}

// ---------------------------------------------------------------------------
// gemm64 (phase 1): C(bf16) = A @ B, 64x64 tile, LDS-staged (verified).
// EPI==0: C *= rs[(row&63)*ldrs+col]; EPI==1: C += bias[col].
// ---------------------------------------------------------------------------
template<int EPI, bool AF32, bool BF32>
__global__ __launch_bounds__(256) void gemm64(
    const void* __restrict__ A, int lda,
    const void* __restrict__ B1, int ldb1,
    const float* __restrict__ rs1, int ldrs1,
    const float* __restrict__ bias,
    unsigned short* __restrict__ C, int ldc, int K)
{
  __shared__ unsigned short As[64][48];
  __shared__ unsigned short Bs[64][48];
  const int tid = threadIdx.x;
  const int n0 = blockIdx.x * 64;
  const int m0 = blockIdx.y * 64;
  const int wv = tid >> 6, lane = tid & 63;
  const int lh = lane & 15, q8 = (lane >> 4) * 8;
  const int arow = tid >> 2, acol = (tid & 3) * 8;
  const int brow = tid >> 3, bcol = (tid & 7) * 8;
  f32x4 acc[4] = {{0,0,0,0},{0,0,0,0},{0,0,0,0},{0,0,0,0}};

  for (int k0 = 0; k0 < K; k0 += 32) {
    unsigned short av[8], bv[8];
    load8<AF32>(A, (size_t)(m0 + arow) * lda + (k0 + acol), av);
    load8<BF32>(B1, (size_t)(k0 + brow) * ldb1 + (n0 + bcol), bv);
    __syncthreads();
    *(uint4*)(&As[arow][acol]) = *(const uint4*)av;
    #pragma unroll
    for (int i = 0; i < 8; ++i) Bs[bcol + i][brow] = bv[i];
    __syncthreads();
    short8 af = *(const short8*)(&As[wv * 16 + lh][q8]);
    #pragma unroll
    for (int nt = 0; nt < 4; ++nt) {
      short8 bf = *(const short8*)(&Bs[nt * 16 + lh][q8]);
      acc[nt] = __builtin_amdgcn_mfma_f32_16x16x32_bf16(af, bf, acc[nt], 0, 0, 0);
    }
  }

  #pragma unroll
  for (int nt = 0; nt < 4; ++nt) {
    #pragma unroll
    for (int r = 0; r < 4; ++r) {
      int row = m0 + wv * 16 + (lane >> 4) * 4 + r;
      int colc = nt * 16 + lh;
      float v = acc[nt][r];
      if (EPI == 0) v *= rs1[(size_t)(row & 63) * ldrs1 + (n0 + colc)];
      else          v += bias[n0 + colc];
      C[(size_t)row * ldc + (n0 + colc)] = f2bf(v);
    }
  }
}

// ---------------------------------------------------------------------------
// k_comb: per-batch combined matrix  C_b[i][c] = sum_k W1[i][off1+k] *
//         S[b][offS+k] * W2[k][c].   Grid (8, 8, 64), 256 thr, K = 512.
// ---------------------------------------------------------------------------
__global__ __launch_bounds__(256) void k_comb(
    const float* __restrict__ W1, int ld1, int off1,  // [512][ld1]
    const float* __restrict__ W2,                     // [512][512]
    const float* __restrict__ S, int ldS, int offS,   // [64][ldS]
    unsigned short* __restrict__ Cout)                // [64][512][512] bf16
{
  __shared__ unsigned short As[64][48];
  __shared__ unsigned short Bs[64][48];
  const int tid = threadIdx.x;
  const int n0 = blockIdx.x * 64;
  const int m0 = blockIdx.y * 64;
  const int b  = blockIdx.z;
  const int wv = tid >> 6, lane = tid & 63;
  const int lh = lane & 15, q8 = (lane >> 4) * 8;
  const int arow = tid >> 2, acol = (tid & 3) * 8;
  const int brow = tid >> 3, bcol = (tid & 7) * 8;
  const float* sv = S + (size_t)b * ldS + offS;
  f32x4 acc[4] = {{0,0,0,0},{0,0,0,0},{0,0,0,0},{0,0,0,0}};

  for (int k0 = 0; k0 < 512; k0 += 32) {
    unsigned short av[8], bv[8];
    {
      const float* p = W1 + (size_t)(m0 + arow) * ld1 + off1 + k0 + acol;
      float4 a = ((const float4*)p)[0], c2 = ((const float4*)p)[1];
      av[0]=f2bf(a.x); av[1]=f2bf(a.y); av[2]=f2bf(a.z); av[3]=f2bf(a.w);
      av[4]=f2bf(c2.x); av[5]=f2bf(c2.y); av[6]=f2bf(c2.z); av[7]=f2bf(c2.w);
    }
    {
      float sk = sv[k0 + brow];
      const float* p = W2 + (size_t)(k0 + brow) * 512 + n0 + bcol;
      float4 a = ((const float4*)p)[0], c2 = ((const float4*)p)[1];
      bv[0]=f2bf(a.x*sk); bv[1]=f2bf(a.y*sk); bv[2]=f2bf(a.z*sk); bv[3]=f2bf(a.w*sk);
      bv[4]=f2bf(c2.x*sk); bv[5]=f2bf(c2.y*sk); bv[6]=f2bf(c2.z*sk); bv[7]=f2bf(c2.w*sk);
    }
    __syncthreads();
    *(uint4*)(&As[arow][acol]) = *(const uint4*)av;
    #pragma unroll
    for (int i = 0; i < 8; ++i) Bs[bcol + i][brow] = bv[i];
    __syncthreads();
    short8 af = *(const short8*)(&As[wv * 16 + lh][q8]);
    #pragma unroll
    for (int nt = 0; nt < 4; ++nt) {
      short8 bf = *(const short8*)(&Bs[nt * 16 + lh][q8]);
      acc[nt] = __builtin_amdgcn_mfma_f32_16x16x32_bf16(af, bf, acc[nt], 0, 0, 0);
    }
  }

  #pragma unroll
  for (int nt = 0; nt < 4; ++nt) {
    #pragma unroll
    for (int r = 0; r < 4; ++r) {
      int row = m0 + wv * 16 + (lane >> 4) * 4 + r;
      int col = n0 + nt * 16 + lh;
      Cout[(size_t)b * 262144 + (size_t)row * 512 + col] = f2bf(acc[nt][r]);
    }
  }
}

// ---------------------------------------------------------------------------
// group barrier: monotone-epoch counter, agent-scope atomics, no fences.
// ---------------------------------------------------------------------------
static __device__ __forceinline__ void gbar(int* bar, int target) {
  asm volatile("s_waitcnt vmcnt(0)" ::: "memory");
  __syncthreads();
  if (threadIdx.x == 0) {
    __hip_atomic_fetch_add(bar, 1, __ATOMIC_RELAXED, __HIP_MEMORY_SCOPE_AGENT);
    while (__hip_atomic_load(bar, __ATOMIC_RELAXED, __HIP_MEMORY_SCOPE_AGENT) < target)
      __builtin_amdgcn_s_sleep(1);
  }
  __syncthreads();
}

static __device__ __forceinline__ void accum8(float* a, float hk, uint4 v) {
  unsigned u0 = v.x, u1 = v.y, u2 = v.z, u3 = v.w;
  a[0] += hk * __builtin_bit_cast(float, u0 << 16);
  a[1] += hk * __builtin_bit_cast(float, u0 & 0xffff0000u);
  a[2] += hk * __builtin_bit_cast(float, u1 << 16);
  a[3] += hk * __builtin_bit_cast(float, u1 & 0xffff0000u);
  a[4] += hk * __builtin_bit_cast(float, u2 << 16);
  a[5] += hk * __builtin_bit_cast(float, u2 & 0xffff0000u);
  a[6] += hk * __builtin_bit_cast(float, u3 << 16);
  a[7] += hk * __builtin_bit_cast(float, u3 & 0xffff0000u);
}

// ---------------------------------------------------------------------------
// k_scan2: 512-step scan via per-batch GEMV on combined matrices.
// Grid = 512 WGs x 512 thr (2 WGs/CU, 16 waves/CU).  WG g: batch b = g>>3,
// column octet o = g&7 (cols [o*64, o*64+64)).  Thread t: chunk = t&7 (col
// octet within the 64), ph = t>>3 in [0,64) (k = ph + 64j, j in [0,8)).
// One 8-WG barrier per step; h exchanged via double-buffered bypass buffer;
// master h (f32) lives in gate-thread registers (t<64).
// ---------------------------------------------------------------------------
__global__ __launch_bounds__(512) void k_scan2(
    const unsigned short* __restrict__ Az,   // [64][512][512] bf16 (row=k, col=out)
    const unsigned short* __restrict__ Ar,
    const unsigned short* __restrict__ Ah,
    const unsigned short* __restrict__ ZRx,  // [T*64][1024] bf16
    const unsigned short* __restrict__ Hx,   // [T*64][512] bf16
    const float* __restrict__ mask,          // [T*64]
    unsigned short* hbuf,                    // [2][64][512] bf16 (rw, cross-WG)
    float* out, int* bar)
{
  const int g = blockIdx.x;
  const int b = g >> 3;
  const int o = g & 7;
  const int c0 = o * 64;
  const int t = threadIdx.x;
  const int chunk = t & 7;
  const int ph = t >> 3;                 // [0,64)
  __shared__ float hs[512];
  __shared__ float part[64][8][25];      // [ph][chunk][3*8], padded stride 25
  int* mybar = bar + b * 32;             // 128B-separated counters

  const size_t mbase = (size_t)b * 262144 + (size_t)ph * 512 + c0 + chunk * 8;
  const unsigned short* pz0 = Az + mbase;
  const unsigned short* pr0 = Ar + mbase;
  const unsigned short* pv0 = Ah + mbase;

  float hold = 0.f;  // master h (f32) for col c0+t, threads t<64
  int ep = 0;

  for (int tm = 0; tm < T_LEN; ++tm) {
    const int cur = tm & 1;
    const size_t itb = (size_t)tm * BATCH + b;
    // prefetch gate operands (latency hidden under GEMV)
    float g_zx = 0.f, g_rx = 0.f, g_hx = 0.f, g_m = 0.f;
    if (t < 64) {
      int gc = c0 + t;
      g_zx = bf2f(ZRx[itb * 1024 + gc]);
      g_rx = bf2f(ZRx[itb * 1024 + 512 + gc]);
      g_hx = bf2f(Hx[itb * 512 + gc]);
      g_m  = mask[itb];
    }
    // full h -> LDS (bypass read; bf16 -> f32)
    if (t < 256) {
      unsigned v = __hip_atomic_load(
          (const unsigned*)(hbuf + ((size_t)cur * 64 + b) * 512) + t,
          __ATOMIC_RELAXED, __HIP_MEMORY_SCOPE_AGENT);
      hs[2 * t]     = bf2f((unsigned short)(v & 0xffffu));
      hs[2 * t + 1] = bf2f((unsigned short)(v >> 16));
    }
    __syncthreads();

    // GEMV partials: 8 k's per thread (fully unrolled -> 24 loads in flight),
    // 8 cols, 3 matrices
    float az[8] = {0,0,0,0,0,0,0,0};
    float ar[8] = {0,0,0,0,0,0,0,0};
    float av[8] = {0,0,0,0,0,0,0,0};
    #pragma unroll
    for (int j = 0; j < 8; ++j) {
      float hk = hs[ph + 64 * j];
      uint4 vz = *(const uint4*)(pz0 + (size_t)j * 64 * 512);
      uint4 vr = *(const uint4*)(pr0 + (size_t)j * 64 * 512);
      uint4 vv = *(const uint4*)(pv0 + (size_t)j * 64 * 512);
      accum8(az, hk, vz);
      accum8(ar, hk, vr);
      accum8(av, hk, vv);
    }
    #pragma unroll
    for (int e = 0; e < 8; ++e) {
      part[ph][chunk][e]      = az[e];
      part[ph][chunk][8 + e]  = ar[e];
      part[ph][chunk][16 + e] = av[e];
    }
    __syncthreads();

    // gates: threads 0..63 own one column each
    if (t < 64) {
      int gc = c0 + t;
      int ch = t >> 3, e = t & 7;
      float sz = 0.f, sr = 0.f, sh = 0.f;
      #pragma unroll 8
      for (int p = 0; p < 64; ++p) {
        sz += part[p][ch][e];
        sr += part[p][ch][8 + e];
        sh += part[p][ch][16 + e];
      }
      float z  = sigmoid_f(sz + g_zx);
      float r  = sigmoid_f(sr + g_rx);
      float hv = tanh_f(g_hx + r * sh);
      float hnew = (1.f - z) * hv + z * hold;
      hnew = g_m * hnew + (1.f - g_m) * hold;
      hold = hnew;
      out[itb * 512 + gc] = hnew;
      if (tm == T_LEN - 1)
        out[(size_t)T_LEN * BATCH * 512 + (size_t)b * 512 + gc] = hnew;
      bstore_u16(hbuf + ((size_t)(cur ^ 1) * 64 + b) * 512 + gc, f2bf(hnew));
    }
    ++ep;
    gbar(mybar, 8 * ep);
  }
}

// ---------------------------------------------------------------------------
extern "C" void kernel_launch(void* const* d_in, const int* in_sizes, int n_in,
                              void* d_out, int out_size, void* d_ws, size_t ws_size,
                              hipStream_t stream) {
  (void)in_sizes; (void)n_in; (void)out_size; (void)ws_size;
  const float* x        = (const float*)d_in[0];
  const float* topic    = (const float*)d_in[1];
  const float* mask     = (const float*)d_in[2];
  const float* W_x2zr   = (const float*)d_in[3];
  const float* W_tp2zrx = (const float*)d_in[4];
  const float* W_xtp2z  = (const float*)d_in[5];
  const float* b_xtp2z  = (const float*)d_in[6];
  const float* W_xtp2r  = (const float*)d_in[7];
  const float* b_xtp2r  = (const float*)d_in[8];
  const float* W_h2zr   = (const float*)d_in[9];
  const float* W_tp2zrh = (const float*)d_in[10];
  const float* W_htp2z  = (const float*)d_in[11];
  const float* W_htp2r  = (const float*)d_in[12];
  const float* W_x2h    = (const float*)d_in[13];
  const float* W_tp2hx  = (const float*)d_in[14];
  const float* W_xtp2h  = (const float*)d_in[15];
  const float* b_xtp2h  = (const float*)d_in[16];
  const float* W_h2h    = (const float*)d_in[17];
  const float* W_tp2hh  = (const float*)d_in[18];
  const float* W_htp2h  = (const float*)d_in[19];
  float* out = (float*)d_out;

  // ---- workspace carve (~194 MiB) ----
  char* w = (char*)d_ws;
  int*            bar  = (int*)w;            w += 8192;                       // 64 x 128B counters
  unsigned short* hbuf = (unsigned short*)w; w += (size_t)2 * BATCH * 512 * 2; // 128 KB
  // ^ [bar|hbuf] contiguous: one memset zeroes both.
  float* tzx = (float*)w;           w += (size_t)BATCH * 1024 * 4;
  float* tzh = (float*)w;           w += (size_t)BATCH * 1024 * 4;
  float* thx = (float*)w;           w += (size_t)BATCH * 512 * 4;
  float* thh = (float*)w;           w += (size_t)BATCH * 512 * 4;
  unsigned short* ZRxtp = (unsigned short*)w; w += (size_t)T_LEN * BATCH * 1024 * 2; // 64 MiB
  unsigned short* Hxtp  = (unsigned short*)w; w += (size_t)T_LEN * BATCH * 512 * 2;  // 32 MiB
  unsigned short* SCR   = (unsigned short*)w; w += (size_t)T_LEN * BATCH * 1024 * 2; // 64 MiB
  unsigned short* AhM   = (unsigned short*)w; w += (size_t)BATCH * 512 * 512 * 2;    // 32 MiB
  // SCR: phase-1 staging (ZRs, then Xhs), afterwards Az|Ar (2 x 32 MiB).
  unsigned short* ZRs = SCR;
  unsigned short* Xhs = SCR;
  unsigned short* AzM = SCR;
  unsigned short* ArM = SCR + (size_t)BATCH * 512 * 512;

  const int M = T_LEN * BATCH;  // 32768

  hipMemsetAsync(bar, 0, 8192 + (size_t)2 * BATCH * 512 * 2, stream);

  // ---- phase 1: topic projections + x-side GEMM chain ----
  k_topic<<<BATCH, 256, 0, stream>>>(topic, W_tp2zrx, W_tp2zrh, W_tp2hx, W_tp2hh,
                                     tzx, tzh, thx, thh);
  gemm64<0, true, true><<<dim3(1024/64, M/64), 256, 0, stream>>>(
      x, DIN, W_x2zr, 1024, tzx, 1024, nullptr, ZRs, 1024, DIN);
  gemm64<1, false, true><<<dim3(512/64, M/64), 256, 0, stream>>>(
      ZRs, 1024, W_xtp2z, 512, nullptr, 0, b_xtp2z, ZRxtp, 1024, 512);
  gemm64<1, false, true><<<dim3(512/64, M/64), 256, 0, stream>>>(
      ZRs + 512, 1024, W_xtp2r, 512, nullptr, 0, b_xtp2r, ZRxtp + 512, 1024, 512);
  gemm64<0, true, true><<<dim3(512/64, M/64), 256, 0, stream>>>(
      x, DIN, W_x2h, 512, thx, 512, nullptr, Xhs, 512, DIN);
  gemm64<1, false, true><<<dim3(512/64, M/64), 256, 0, stream>>>(
      Xhs, 512, W_xtp2h, 512, nullptr, 0, b_xtp2h, Hxtp, 512, 512);

  // ---- combined per-batch recurrent matrices (overwrite SCR after use) ----
  k_comb<<<dim3(8, 8, 64), 256, 0, stream>>>(W_h2zr, 1024,   0, W_htp2z, tzh, 1024,   0, AzM);
  k_comb<<<dim3(8, 8, 64), 256, 0, stream>>>(W_h2zr, 1024, 512, W_htp2r, tzh, 1024, 512, ArM);
  k_comb<<<dim3(8, 8, 64), 256, 0, stream>>>(W_h2h,   512,   0, W_htp2h, thh,  512,   0, AhM);

  // ---- phase 2: per-batch GEMV scan, 64 batches x 8 WGs, 2 WGs/CU ----
  k_scan2<<<512, 512, 0, stream>>>(AzM, ArM, AhM, ZRxtp, Hxtp, mask,
                                   hbuf, out, bar);
}

// Round 4
// 4185.054 us; speedup vs baseline: 4.0520x; 1.1888x over previous
//
#include <hip/hip_runtime.h>
#include <stdint.h>
#include <stddef.h>

// TPGRUCell forward, MI355X gfx950.
// R5: combined per-batch recurrent matrices (Az/Ar/Ah) -> per-batch GEMV scan.
// R6: 512 WGs (8 per batch, 64 cols each), L2-resident A slices.
// R7 (this round): the scan step was sync-latency-bound (~5 of 7.6us).
//  - gbar + hbuf replaced by a fused tag-published exchange: producer writes
//    its 64 h-cols (32 dwords, MALL bypass) + vmcnt drain + tag store;
//    consumers spin on 8 tags then load data. Removes atomic-add RT,
//    add serialization, and the separate h-load RT.
//  - the 192-output partial reduction is distributed over 192 threads
//    (was a serial 192-read chain in wave 0), shortening the publish path.
//  - no trailing workgroup barrier: waves 1-7 run ahead to the next spin.

#define T_LEN 512
#define BATCH 64
#define DIN   512
#define DH    512
#define DT    128

typedef __attribute__((ext_vector_type(8))) short short8;
typedef __attribute__((ext_vector_type(4))) float f32x4;

static __device__ __forceinline__ float bf2f(unsigned short u) {
  unsigned v = ((unsigned)u) << 16;
  return __builtin_bit_cast(float, v);
}
static __device__ __forceinline__ unsigned short f2bf(float f) {
  unsigned v = __builtin_bit_cast(unsigned, f);
  unsigned r = (v + 0x7fffu + ((v >> 16) & 1u)) >> 16;
  return (unsigned short)r;
}
static __device__ __forceinline__ float sigmoid_f(float x) {
  return 1.f / (1.f + __expf(-x));
}
static __device__ __forceinline__ float tanh_f(float x) {
  float e = __expf(-2.f * fabsf(x));
  float t = (1.f - e) / (1.f + e);
  return copysignf(t, x);
}

template<bool F32>
static __device__ __forceinline__ void load8(const void* p, size_t off, unsigned short* d) {
  if (F32) {
    const float4* q = (const float4*)((const float*)p + off);
    float4 a = q[0], b = q[1];
    d[0] = f2bf(a.x); d[1] = f2bf(a.y); d[2] = f2bf(a.z); d[3] = f2bf(a.w);
    d[4] = f2bf(b.x); d[5] = f2bf(b.y); d[6] = f2bf(b.z); d[7] = f2bf(b.w);
  } else {
    *(uint4*)d = *(const uint4*)((const unsigned short*)p + off);
  }
}

// ---------------------------------------------------------------------------
// k_topic: the four topic@W projections, all f32.
// ---------------------------------------------------------------------------
__global__ __launch_bounds__(256) void k_topic(
    const float* __restrict__ topic,
    const float* __restrict__ Wzx,  // [128][1024]
    const float* __restrict__ Wzh,  // [128][1024]
    const float* __restrict__ Whx,  // [128][512]
    const float* __restrict__ Whh,  // [128][512]
    float* __restrict__ tzx, float* __restrict__ tzh,
    float* __restrict__ thx, float* __restrict__ thh)
{
  const int b = blockIdx.x;
  __shared__ float tp[DT];
  if (threadIdx.x < DT) tp[threadIdx.x] = topic[b * DT + threadIdx.x];
  __syncthreads();
  for (int c = threadIdx.x; c < 3072; c += 256) {
    const float* wp; float* op; int ld, cc;
    if (c < 1024)      { wp = Wzx; ld = 1024; cc = c;        op = &tzx[b*1024 + cc]; }
    else if (c < 2048) { wp = Wzh; ld = 1024; cc = c - 1024; op = &tzh[b*1024 + cc]; }
    else if (c < 2560) { wp = Whx; ld = 512;  cc = c - 2048; op = &thx[b*512  + cc]; }
    else               { wp = Whh; ld = 512;  cc = c - 2560; op = &thh[b*512  + cc]; }
    float acc = 0.f;
    #pragma unroll 4
    for (int k = 0; k < DT; ++k) acc += tp[k] * wp[(size_t)k * ld + cc];
    *op = acc;
  }
}

// ---------------------------------------------------------------------------
// gemm64 (phase 1): C(bf16) = A @ B, 64x64 tile, LDS-staged (verified).
// EPI==0: C *= rs[(row&63)*ldrs+col]; EPI==1: C += bias[col].
// ---------------------------------------------------------------------------
template<int EPI, bool AF32, bool BF32>
__global__ __launch_bounds__(256) void gemm64(
    const void* __restrict__ A, int lda,
    const void* __restrict__ B1, int ldb1,
    const float* __restrict__ rs1, int ldrs1,
    const float* __restrict__ bias,
    unsigned short* __restrict__ C, int ldc, int K)
{
  __shared__ unsigned short As[64][48];
  __shared__ unsigned short Bs[64][48];
  const int tid = threadIdx.x;
  const int n0 = blockIdx.x * 64;
  const int m0 = blockIdx.y * 64;
  const int wv = tid >> 6, lane = tid & 63;
  const int lh = lane & 15, q8 = (lane >> 4) * 8;
  const int arow = tid >> 2, acol = (tid & 3) * 8;
  const int brow = tid >> 3, bcol = (tid & 7) * 8;
  f32x4 acc[4] = {{0,0,0,0},{0,0,0,0},{0,0,0,0},{0,0,0,0}};

  for (int k0 = 0; k0 < K; k0 += 32) {
    unsigned short av[8], bv[8];
    load8<AF32>(A, (size_t)(m0 + arow) * lda + (k0 + acol), av);
    load8<BF32>(B1, (size_t)(k0 + brow) * ldb1 + (n0 + bcol), bv);
    __syncthreads();
    *(uint4*)(&As[arow][acol]) = *(const uint4*)av;
    #pragma unroll
    for (int i = 0; i < 8; ++i) Bs[bcol + i][brow] = bv[i];
    __syncthreads();
    short8 af = *(const short8*)(&As[wv * 16 + lh][q8]);
    #pragma unroll
    for (int nt = 0; nt < 4; ++nt) {
      short8 bf = *(const short8*)(&Bs[nt * 16 + lh][q8]);
      acc[nt] = __builtin_amdgcn_mfma_f32_16x16x32_bf16(af, bf, acc[nt], 0, 0, 0);
    }
  }

  #pragma unroll
  for (int nt = 0; nt < 4; ++nt) {
    #pragma unroll
    for (int r = 0; r < 4; ++r) {
      int row = m0 + wv * 16 + (lane >> 4) * 4 + r;
      int colc = nt * 16 + lh;
      float v = acc[nt][r];
      if (EPI == 0) v *= rs1[(size_t)(row & 63) * ldrs1 + (n0 + colc)];
      else          v += bias[n0 + colc];
      C[(size_t)row * ldc + (n0 + colc)] = f2bf(v);
    }
  }
}

// ---------------------------------------------------------------------------
// k_comb: per-batch combined matrix  C_b[i][c] = sum_k W1[i][off1+k] *
//         S[b][offS+k] * W2[k][c].   Grid (8, 8, 64), 256 thr, K = 512.
// ---------------------------------------------------------------------------
__global__ __launch_bounds__(256) void k_comb(
    const float* __restrict__ W1, int ld1, int off1,  // [512][ld1]
    const float* __restrict__ W2,                     // [512][512]
    const float* __restrict__ S, int ldS, int offS,   // [64][ldS]
    unsigned short* __restrict__ Cout)                // [64][512][512] bf16
{
  __shared__ unsigned short As[64][48];
  __shared__ unsigned short Bs[64][48];
  const int tid = threadIdx.x;
  const int n0 = blockIdx.x * 64;
  const int m0 = blockIdx.y * 64;
  const int b  = blockIdx.z;
  const int wv = tid >> 6, lane = tid & 63;
  const int lh = lane & 15, q8 = (lane >> 4) * 8;
  const int arow = tid >> 2, acol = (tid & 3) * 8;
  const int brow = tid >> 3, bcol = (tid & 7) * 8;
  const float* sv = S + (size_t)b * ldS + offS;
  f32x4 acc[4] = {{0,0,0,0},{0,0,0,0},{0,0,0,0},{0,0,0,0}};

  for (int k0 = 0; k0 < 512; k0 += 32) {
    unsigned short av[8], bv[8];
    {
      const float* p = W1 + (size_t)(m0 + arow) * ld1 + off1 + k0 + acol;
      float4 a = ((const float4*)p)[0], c2 = ((const float4*)p)[1];
      av[0]=f2bf(a.x); av[1]=f2bf(a.y); av[2]=f2bf(a.z); av[3]=f2bf(a.w);
      av[4]=f2bf(c2.x); av[5]=f2bf(c2.y); av[6]=f2bf(c2.z); av[7]=f2bf(c2.w);
    }
    {
      float sk = sv[k0 + brow];
      const float* p = W2 + (size_t)(k0 + brow) * 512 + n0 + bcol;
      float4 a = ((const float4*)p)[0], c2 = ((const float4*)p)[1];
      bv[0]=f2bf(a.x*sk); bv[1]=f2bf(a.y*sk); bv[2]=f2bf(a.z*sk); bv[3]=f2bf(a.w*sk);
      bv[4]=f2bf(c2.x*sk); bv[5]=f2bf(c2.y*sk); bv[6]=f2bf(c2.z*sk); bv[7]=f2bf(c2.w*sk);
    }
    __syncthreads();
    *(uint4*)(&As[arow][acol]) = *(const uint4*)av;
    #pragma unroll
    for (int i = 0; i < 8; ++i) Bs[bcol + i][brow] = bv[i];
    __syncthreads();
    short8 af = *(const short8*)(&As[wv * 16 + lh][q8]);
    #pragma unroll
    for (int nt = 0; nt < 4; ++nt) {
      short8 bf = *(const short8*)(&Bs[nt * 16 + lh][q8]);
      acc[nt] = __builtin_amdgcn_mfma_f32_16x16x32_bf16(af, bf, acc[nt], 0, 0, 0);
    }
  }

  #pragma unroll
  for (int nt = 0; nt < 4; ++nt) {
    #pragma unroll
    for (int r = 0; r < 4; ++r) {
      int row = m0 + wv * 16 + (lane >> 4) * 4 + r;
      int col = n0 + nt * 16 + lh;
      Cout[(size_t)b * 262144 + (size_t)row * 512 + col] = f2bf(acc[nt][r]);
    }
  }
}

static __device__ __forceinline__ void accum8(float* a, float hk, uint4 v) {
  unsigned u0 = v.x, u1 = v.y, u2 = v.z, u3 = v.w;
  a[0] += hk * __builtin_bit_cast(float, u0 << 16);
  a[1] += hk * __builtin_bit_cast(float, u0 & 0xffff0000u);
  a[2] += hk * __builtin_bit_cast(float, u1 << 16);
  a[3] += hk * __builtin_bit_cast(float, u1 & 0xffff0000u);
  a[4] += hk * __builtin_bit_cast(float, u2 << 16);
  a[5] += hk * __builtin_bit_cast(float, u2 & 0xffff0000u);
  a[6] += hk * __builtin_bit_cast(float, u3 << 16);
  a[7] += hk * __builtin_bit_cast(float, u3 & 0xffff0000u);
}

// ---------------------------------------------------------------------------
// k_scan3: 512-step scan via per-batch GEMV on combined matrices.
// Grid = 512 WGs x 512 thr. WG g: batch b = g>>3, col block w = g&7
// (cols [w*64, w*64+64)).
// Exchange: pub[2][64][8][64] u32 regions (32 h-dwords bf16x2 + tag at [32],
// 256B stride). Producer: data stores -> vmcnt(0) -> tag = tm+1 (all MALL
// bypass). Consumer step tm: spin 8 tags >= tm, sync, load data.
// Safety: tag observed => data visible (drain-before-tag + per-address MALL
// order + loads issued after tag read). No clobber: a peer overwrites parity
// p only after all WGs tagged parity p^1, which postdates their reads of p.
// ---------------------------------------------------------------------------
__global__ __launch_bounds__(512) void k_scan3(
    const unsigned short* __restrict__ Az,   // [64][512][512] bf16 (row=k, col=out)
    const unsigned short* __restrict__ Ar,
    const unsigned short* __restrict__ Ah,
    const unsigned short* __restrict__ ZRx,  // [T*64][1024] bf16
    const unsigned short* __restrict__ Hx,   // [T*64][512] bf16
    const float* __restrict__ mask,          // [T*64]
    unsigned* __restrict__ pub,              // [2][64][8][64] u32
    float* out)
{
  const int g = blockIdx.x;
  const int b = g >> 3;
  const int w = g & 7;
  const int c0 = w * 64;
  const int t = threadIdx.x;
  const int chunk = t & 7;
  const int ph = t >> 3;                 // [0,64)
  __shared__ float hs[512];
  __shared__ float part[64][8][25];      // [ph][chunk][3*8], padded stride 25
  __shared__ float red[192];             // reduced sums: [gate*64 + col]

  const size_t mbase = (size_t)b * 262144 + (size_t)ph * 512 + c0 + chunk * 8;
  const unsigned short* pz0 = Az + mbase;
  const unsigned short* pr0 = Ar + mbase;
  const unsigned short* pv0 = Ah + mbase;

  unsigned* pubB0 = pub + (size_t)b * 512;           // parity 0: [8][64]
  unsigned* pubB1 = pub + (size_t)(64 + b) * 512;    // parity 1

  float hold = 0.f;  // master h (f32) for col c0+t, threads t<64
  for (int tm = 0; tm < T_LEN; ++tm) {
    unsigned* pubC = (tm & 1) ? pubB1 : pubB0;   // consume (state after tm steps)
    unsigned* pubP = (tm & 1) ? pubB0 : pubB1;   // produce (state after tm+1)
    const size_t itb = (size_t)tm * BATCH + b;

    // gate-operand prefetch (HBM stream; hides under peer skew/spin)
    float g_zx = 0.f, g_rx = 0.f, g_hx = 0.f, g_m = 0.f;
    if (t < 64) {
      int gc = c0 + t;
      g_zx = bf2f(ZRx[itb * 1024 + gc]);
      g_rx = bf2f(ZRx[itb * 1024 + 512 + gc]);
      g_hx = bf2f(Hx[itb * 512 + gc]);
      g_m  = mask[itb];
    }
    // spin: lanes 0..7 poll the 8 region tags of this parity
    if (t < 8) {
      const unsigned* tagp = pubC + t * 64 + 32;
      while ((int)__hip_atomic_load(tagp, __ATOMIC_RELAXED, __HIP_MEMORY_SCOPE_AGENT) < tm)
        ;
    }
    __syncthreads();
    // h data -> LDS (bypass read; bf16x2 -> f32)
    if (t < 256) {
      unsigned v = __hip_atomic_load(pubC + (t >> 5) * 64 + (t & 31),
                                     __ATOMIC_RELAXED, __HIP_MEMORY_SCOPE_AGENT);
      int col = (t >> 5) * 64 + (t & 31) * 2;
      hs[col]     = bf2f((unsigned short)(v & 0xffffu));
      hs[col + 1] = bf2f((unsigned short)(v >> 16));
    }
    __syncthreads();

    // GEMV partials: 8 k's per thread (fully unrolled), 8 cols, 3 matrices
    float az[8] = {0,0,0,0,0,0,0,0};
    float ar[8] = {0,0,0,0,0,0,0,0};
    float av[8] = {0,0,0,0,0,0,0,0};
    #pragma unroll
    for (int j = 0; j < 8; ++j) {
      float hk = hs[ph + 64 * j];
      uint4 vz = *(const uint4*)(pz0 + (size_t)j * 64 * 512);
      uint4 vr = *(const uint4*)(pr0 + (size_t)j * 64 * 512);
      uint4 vv = *(const uint4*)(pv0 + (size_t)j * 64 * 512);
      accum8(az, hk, vz);
      accum8(ar, hk, vr);
      accum8(av, hk, vv);
    }
    #pragma unroll
    for (int e = 0; e < 8; ++e) {
      part[ph][chunk][e]      = az[e];
      part[ph][chunk][8 + e]  = ar[e];
      part[ph][chunk][16 + e] = av[e];
    }
    __syncthreads();

    // distributed reduction: 192 threads, one (gate,col) output each
    if (t < 192) {
      int c = t & 63;
      int ch = c >> 3;
      int e  = (t >> 6) * 8 + (c & 7);
      float s = 0.f;
      #pragma unroll 16
      for (int p = 0; p < 64; ++p) s += part[p][ch][e];
      red[t] = s;
    }
    __syncthreads();

    // gates + publish: wave 0 only (no trailing workgroup barrier)
    if (t < 64) {
      float z  = sigmoid_f(red[t] + g_zx);
      float r  = sigmoid_f(red[64 + t] + g_rx);
      float hv = tanh_f(g_hx + r * red[128 + t]);
      float hnew = (1.f - z) * hv + z * hold;
      hnew = g_m * hnew + (1.f - g_m) * hold;
      hold = hnew;
      int gc = c0 + t;
      out[itb * 512 + gc] = hnew;
      if (tm == T_LEN - 1)
        out[(size_t)T_LEN * BATCH * 512 + (size_t)b * 512 + gc] = hnew;
      // pack 64 bf16 cols into 32 dwords via wave shuffles, publish + tag
      int hb = (int)f2bf(hnew);
      unsigned lo = (unsigned)__shfl(hb, 2 * t);
      unsigned hi = (unsigned)__shfl(hb, 2 * t + 1);
      if (t < 32)
        __hip_atomic_store(pubP + w * 64 + t, lo | (hi << 16),
                           __ATOMIC_RELAXED, __HIP_MEMORY_SCOPE_AGENT);
      asm volatile("s_waitcnt vmcnt(0)" ::: "memory");
      if (t == 0)
        __hip_atomic_store(pubP + w * 64 + 32, (unsigned)(tm + 1),
                           __ATOMIC_RELAXED, __HIP_MEMORY_SCOPE_AGENT);
    }
    // waves 1..7 run ahead; they block at the next spin's __syncthreads,
    // which wave 0 joins only after publishing. part/hs overwrite is gated
    // by that barrier, so no trailing barrier is needed here.
  }
}

// ---------------------------------------------------------------------------
extern "C" void kernel_launch(void* const* d_in, const int* in_sizes, int n_in,
                              void* d_out, int out_size, void* d_ws, size_t ws_size,
                              hipStream_t stream) {
  (void)in_sizes; (void)n_in; (void)out_size; (void)ws_size;
  const float* x        = (const float*)d_in[0];
  const float* topic    = (const float*)d_in[1];
  const float* mask     = (const float*)d_in[2];
  const float* W_x2zr   = (const float*)d_in[3];
  const float* W_tp2zrx = (const float*)d_in[4];
  const float* W_xtp2z  = (const float*)d_in[5];
  const float* b_xtp2z  = (const float*)d_in[6];
  const float* W_xtp2r  = (const float*)d_in[7];
  const float* b_xtp2r  = (const float*)d_in[8];
  const float* W_h2zr   = (const float*)d_in[9];
  const float* W_tp2zrh = (const float*)d_in[10];
  const float* W_htp2z  = (const float*)d_in[11];
  const float* W_htp2r  = (const float*)d_in[12];
  const float* W_x2h    = (const float*)d_in[13];
  const float* W_tp2hx  = (const float*)d_in[14];
  const float* W_xtp2h  = (const float*)d_in[15];
  const float* b_xtp2h  = (const float*)d_in[16];
  const float* W_h2h    = (const float*)d_in[17];
  const float* W_tp2hh  = (const float*)d_in[18];
  const float* W_htp2h  = (const float*)d_in[19];
  float* out = (float*)d_out;

  // ---- workspace carve (~194 MiB) ----
  char* w = (char*)d_ws;
  unsigned* pub = (unsigned*)w;      w += (size_t)2 * 64 * 8 * 64 * 4;  // 256 KB
  float* tzx = (float*)w;           w += (size_t)BATCH * 1024 * 4;
  float* tzh = (float*)w;           w += (size_t)BATCH * 1024 * 4;
  float* thx = (float*)w;           w += (size_t)BATCH * 512 * 4;
  float* thh = (float*)w;           w += (size_t)BATCH * 512 * 4;
  unsigned short* ZRxtp = (unsigned short*)w; w += (size_t)T_LEN * BATCH * 1024 * 2; // 64 MiB
  unsigned short* Hxtp  = (unsigned short*)w; w += (size_t)T_LEN * BATCH * 512 * 2;  // 32 MiB
  unsigned short* SCR   = (unsigned short*)w; w += (size_t)T_LEN * BATCH * 1024 * 2; // 64 MiB
  unsigned short* AhM   = (unsigned short*)w; w += (size_t)BATCH * 512 * 512 * 2;    // 32 MiB
  // SCR: phase-1 staging (ZRs, then Xhs), afterwards Az|Ar (2 x 32 MiB).
  unsigned short* ZRs = SCR;
  unsigned short* Xhs = SCR;
  unsigned short* AzM = SCR;
  unsigned short* ArM = SCR + (size_t)BATCH * 512 * 512;

  const int M = T_LEN * BATCH;  // 32768

  // pub zeroed: tags = 0 ("0 steps complete"), data = 0 (h0 = 0).
  hipMemsetAsync(pub, 0, (size_t)2 * 64 * 8 * 64 * 4, stream);

  // ---- phase 1: topic projections + x-side GEMM chain ----
  k_topic<<<BATCH, 256, 0, stream>>>(topic, W_tp2zrx, W_tp2zrh, W_tp2hx, W_tp2hh,
                                     tzx, tzh, thx, thh);
  gemm64<0, true, true><<<dim3(1024/64, M/64), 256, 0, stream>>>(
      x, DIN, W_x2zr, 1024, tzx, 1024, nullptr, ZRs, 1024, DIN);
  gemm64<1, false, true><<<dim3(512/64, M/64), 256, 0, stream>>>(
      ZRs, 1024, W_xtp2z, 512, nullptr, 0, b_xtp2z, ZRxtp, 1024, 512);
  gemm64<1, false, true><<<dim3(512/64, M/64), 256, 0, stream>>>(
      ZRs + 512, 1024, W_xtp2r, 512, nullptr, 0, b_xtp2r, ZRxtp + 512, 1024, 512);
  gemm64<0, true, true><<<dim3(512/64, M/64), 256, 0, stream>>>(
      x, DIN, W_x2h, 512, thx, 512, nullptr, Xhs, 512, DIN);
  gemm64<1, false, true><<<dim3(512/64, M/64), 256, 0, stream>>>(
      Xhs, 512, W_xtp2h, 512, nullptr, 0, b_xtp2h, Hxtp, 512, 512);

  // ---- combined per-batch recurrent matrices (overwrite SCR after use) ----
  k_comb<<<dim3(8, 8, 64), 256, 0, stream>>>(W_h2zr, 1024,   0, W_htp2z, tzh, 1024,   0, AzM);
  k_comb<<<dim3(8, 8, 64), 256, 0, stream>>>(W_h2zr, 1024, 512, W_htp2r, tzh, 1024, 512, ArM);
  k_comb<<<dim3(8, 8, 64), 256, 0, stream>>>(W_h2h,   512,   0, W_htp2h, thh,  512,   0, AhM);

  // ---- phase 2: per-batch GEMV scan, 64 batches x 8 WGs ----
  k_scan3<<<512, 512, 0, stream>>>(AzM, ArM, AhM, ZRxtp, Hxtp, mask,
                                   pub, out);
}